// Round 20
// baseline (864.940 us; speedup 1.0000x reference)
//
#include <hip/hip_runtime.h>
#include <stdint.h>
#include <math.h>

#define NN 12288
#define DD 128
#define KTOP 31
#define TCAND 64         // candidate set >= top-64 by bf16 key (R0-R19-verified margin)
#define CCAP 128         // compaction capacity
#define RPB 48           // rows per loop-block; grid = 256 = 1 block/CU
#define WPL 16           // waves per loop block (1024 threads -> 4 waves/SIMD)
#define NIT 24           // column iterations: 12288 / (WPL*32)
#define KPROW 1024       // keys per row (128 streams x depth 8); 4 KB = row output prefix

typedef __attribute__((ext_vector_type(8))) short bf16x8;
typedef __attribute__((ext_vector_type(4))) float f32x4;

__device__ __forceinline__ unsigned short f2bf(float x) {  // RNE, no NaN in our data
  unsigned int u = __float_as_uint(x);
  u += 0x7fffu + ((u >> 16) & 1u);
  return (unsigned short)(u >> 16);
}

__device__ __forceinline__ unsigned umed3(unsigned a, unsigned b, unsigned c) {
  unsigned d;
  asm("v_med3_u32 %0, %1, %2, %3" : "=v"(d) : "v"(a), "v"(b), "v"(c));
  return d;
}

#define PINS8(Lx, P) { \
  const unsigned p_ = (P); \
  _Pragma("unroll") \
  for (int i_ = 0; i_ < 7; ++i_) \
    Lx[i_] = umed3(p_, Lx[i_], Lx[i_ + 1]); \
  Lx[7] = Lx[7] > p_ ? Lx[7] : p_; }

#define LKEY(ACC, LX, COLBASE) { \
  _Pragma("unroll") \
  for (int r_ = 0; r_ < 4; ++r_) { \
    unsigned bf_ = f2bf((ACC)[r_]); \
    unsigned s_ = (bf_ & 0x8000u) ? 0u : bf_; \
    unsigned p_k = (s_ << 16) | (unsigned)((COLBASE) + quad * 4 + r_); \
    PINS8(LX, p_k) } }

// one candidate's 8-float gather + exact fp64 dot (order identical to R18/R19)
#define CDOT(CI, P) { \
  if ((CI) < nc) { \
    const int col_ = (int)(scand[wv][CI] & 0xFFFFu); \
    const float* brow_ = hnf + (size_t)col_ * DD + kl; \
    f32x4 b03_ = *(const f32x4*)(brow_); \
    f32x4 b47_ = *(const f32x4*)(brow_ + 4); \
    P = fma((double)a[0], (double)b03_.x, fma((double)a[1], (double)b03_.y, \
        fma((double)a[2], (double)b03_.z, (double)a[3] * (double)b03_.w))); \
    P = fma((double)a[4], (double)b47_.x, fma((double)a[5], (double)b47_.y, \
        fma((double)a[6], (double)b47_.z, fma((double)a[7], (double)b47_.w, P)))); \
  } }

// ---------------- Kernel 0: transpose W1,W2 ----------------
__global__ __launch_bounds__(128)
void wtrans_kernel(const float* __restrict__ W1, const float* __restrict__ W2,
                   float* __restrict__ W1T, float* __restrict__ W2T) {
  const int r = blockIdx.x, c = threadIdx.x;
  W1T[(size_t)c * DD + r] = W1[(size_t)r * DD + c];
  W2T[(size_t)c * DD + r] = W2[(size_t)r * DD + c];
}

// ---------------- Kernel 1: MLP + L2 normalize (byte-identical to R19) ----------------
__global__ __launch_bounds__(256)
void mlp_norm_kernel(const float* __restrict__ feat,
                     const float* __restrict__ W1T, const float* __restrict__ b1,
                     const float* __restrict__ W2T, const float* __restrict__ b2,
                     float* __restrict__ hnf, unsigned short* __restrict__ hnb) {
  __shared__ float  bufA[16][DD];    // 8 KB (f32 input, exact)
  __shared__ float  bufB[16][DD];    // 8 KB (f32 post-ReLU)
  __shared__ double bufC[16][DD];    // 16 KB
  __shared__ double mnorm[16];
  const int t = threadIdx.x;
  const int c = t & 127;
  const int g = t >> 7;
  const int row0 = blockIdx.x * 16 + g * 8;

  #pragma unroll
  for (int rr = 0; rr < 8; ++rr)
    bufA[g * 8 + rr][c] = feat[(size_t)(row0 + rr) * DD + c];
  __syncthreads();

  {
    double acc[8] = {0,0,0,0,0,0,0,0};
    for (int k = 0; k < DD; k += 4) {
      double w0 = (double)W1T[(size_t)k * DD + c];
      double w1 = (double)W1T[(size_t)(k + 1) * DD + c];
      double w2 = (double)W1T[(size_t)(k + 2) * DD + c];
      double w3 = (double)W1T[(size_t)(k + 3) * DD + c];
      #pragma unroll
      for (int rr = 0; rr < 8; ++rr) {
        f32x4 a4 = *(const f32x4*)(&bufA[g * 8 + rr][k]);
        acc[rr] = fma(w0, (double)a4.x, acc[rr]);
        acc[rr] = fma(w1, (double)a4.y, acc[rr]);
        acc[rr] = fma(w2, (double)a4.z, acc[rr]);
        acc[rr] = fma(w3, (double)a4.w, acc[rr]);
      }
    }
    double bb = (double)b1[c];
    #pragma unroll
    for (int rr = 0; rr < 8; ++rr)
      bufB[g * 8 + rr][c] = (float)fmax(acc[rr] + bb, 0.0);
  }
  __syncthreads();
  {
    double acc[8] = {0,0,0,0,0,0,0,0};
    for (int k = 0; k < DD; k += 4) {
      double w0 = (double)W2T[(size_t)k * DD + c];
      double w1 = (double)W2T[(size_t)(k + 1) * DD + c];
      double w2 = (double)W2T[(size_t)(k + 2) * DD + c];
      double w3 = (double)W2T[(size_t)(k + 3) * DD + c];
      #pragma unroll
      for (int rr = 0; rr < 8; ++rr) {
        f32x4 a4 = *(const f32x4*)(&bufB[g * 8 + rr][k]);
        acc[rr] = fma(w0, (double)a4.x, acc[rr]);
        acc[rr] = fma(w1, (double)a4.y, acc[rr]);
        acc[rr] = fma(w2, (double)a4.z, acc[rr]);
        acc[rr] = fma(w3, (double)a4.w, acc[rr]);
      }
    }
    double bb = (double)b2[c];
    #pragma unroll
    for (int rr = 0; rr < 8; ++rr)
      bufC[g * 8 + rr][c] = acc[rr] + bb;
  }
  __syncthreads();

  const int lane = t & 63;
  const int w = t >> 6;
  #pragma unroll
  for (int r2 = 0; r2 < 4; ++r2) {
    int rr = w * 4 + r2;
    double x0 = bufC[rr][lane];
    double x1 = bufC[rr][lane + 64];
    double s = x0 * x0 + x1 * x1;
    #pragma unroll
    for (int d = 1; d < 64; d <<= 1)
      s += __shfl_xor(s, d);
    if (lane == 0) mnorm[rr] = fmax(sqrt(s), 1e-12);
  }
  __syncthreads();
  #pragma unroll
  for (int rr = 0; rr < 8; ++rr) {
    double v = bufC[g * 8 + rr][c] / mnorm[g * 8 + rr];
    float vf = (float)v;
    hnf[(size_t)(row0 + rr) * DD + c] = vf;
    hnb[(size_t)(row0 + rr) * DD + c] = f2bf(vf);
  }
}

// ---------------- Kernel 2: sim MFMA loop + ladders + in-loop zeros (byte-identical to R19) ----------------
__global__ __launch_bounds__(1024)
void simloop_kernel(const unsigned short* __restrict__ hnb,
                    float* __restrict__ out) {
  const int t = threadIdx.x, lane = t & 63, wv = t >> 6;   // wv 0..15
  const int m = lane & 15, quad = lane >> 4;
  const int row0 = blockIdx.x * RPB;
  const int it0 = (int)(((blockIdx.x >> 3) * 3u) % NIT);   // same-XCD phase spread
  const bool pfx = (t < 256);                              // prefix-owning threads

  bf16x8 af0[4], af1[4], af2[4];
  #pragma unroll
  for (int kc = 0; kc < 4; ++kc) {
    af0[kc] = *(const bf16x8*)(hnb + (size_t)(row0 + m) * DD + kc * 32 + quad * 8);
    af1[kc] = *(const bf16x8*)(hnb + (size_t)(row0 + 16 + m) * DD + kc * 32 + quad * 8);
    af2[kc] = *(const bf16x8*)(hnb + (size_t)(row0 + 32 + m) * DD + kc * 32 + quad * 8);
  }

  unsigned LA0[8] = {0,0,0,0,0,0,0,0}, LB0[8] = {0,0,0,0,0,0,0,0};
  unsigned LA1[8] = {0,0,0,0,0,0,0,0}, LB1[8] = {0,0,0,0,0,0,0,0};
  unsigned LA2[8] = {0,0,0,0,0,0,0,0}, LB2[8] = {0,0,0,0,0,0,0,0};

  f32x4* outz = (f32x4*)(out + (size_t)row0 * NN);   // 48 rows = 147456 f32x4
  const f32x4 z = {0.0f, 0.0f, 0.0f, 0.0f};

  for (int itt = 0; itt < NIT; ++itt) {
    int it = itt + it0; if (it >= NIT) it -= NIT;    // staggered column phase
    const int cb = it * (WPL * 32) + wv * 32;
    f32x4 a00 = {0,0,0,0}, a01 = {0,0,0,0};
    f32x4 a10 = {0,0,0,0}, a11 = {0,0,0,0};
    f32x4 a20 = {0,0,0,0}, a21 = {0,0,0,0};
    #pragma unroll
    for (int kc = 0; kc < 4; ++kc) {    // per-kc B loads: caps VGPR for 16-wave block
      bf16x8 b0 = *(const bf16x8*)(hnb + (size_t)(cb + m) * DD + kc * 32 + quad * 8);
      bf16x8 b1 = *(const bf16x8*)(hnb + (size_t)(cb + 16 + m) * DD + kc * 32 + quad * 8);
      a00 = __builtin_amdgcn_mfma_f32_16x16x32_bf16(b0, af0[kc], a00, 0, 0, 0);
      a01 = __builtin_amdgcn_mfma_f32_16x16x32_bf16(b1, af0[kc], a01, 0, 0, 0);
      a10 = __builtin_amdgcn_mfma_f32_16x16x32_bf16(b0, af1[kc], a10, 0, 0, 0);
      a11 = __builtin_amdgcn_mfma_f32_16x16x32_bf16(b1, af1[kc], a11, 0, 0, 0);
      a20 = __builtin_amdgcn_mfma_f32_16x16x32_bf16(b0, af2[kc], a20, 0, 0, 0);
      a21 = __builtin_amdgcn_mfma_f32_16x16x32_bf16(b1, af2[kc], a21, 0, 0, 0);
    }
    // in-loop NT zeros; j==0/j==3 land on row prefixes for t<256 — skipped
    if (!pfx) __builtin_nontemporal_store(z, &outz[it * 6144 + t]);
    __builtin_nontemporal_store(z, &outz[it * 6144 + 1024 + t]);
    __builtin_nontemporal_store(z, &outz[it * 6144 + 2048 + t]);
    if (!pfx) __builtin_nontemporal_store(z, &outz[it * 6144 + 3072 + t]);
    __builtin_nontemporal_store(z, &outz[it * 6144 + 4096 + t]);
    __builtin_nontemporal_store(z, &outz[it * 6144 + 5120 + t]);
    LKEY(a00, LA0, cb)      LKEY(a01, LB0, cb + 16)
    LKEY(a10, LA1, cb)      LKEY(a11, LB1, cb + 16)
    LKEY(a20, LA2, cb)      LKEY(a21, LB2, cb + 16)
  }

  // key dump: no aliasing with the zero stream -> no drain/barrier needed
  const int sbase = (wv * 4 + quad) * 16;   // 64 slots x 16 u32 = 1024 keys/row
  {
    unsigned* d0 = (unsigned*)(out + (size_t)(row0 + m) * NN) + sbase;
    *(uint4*)(d0)     = make_uint4(LA0[0], LA0[1], LA0[2], LA0[3]);
    *(uint4*)(d0 + 4) = make_uint4(LA0[4], LA0[5], LA0[6], LA0[7]);
    *(uint4*)(d0 + 8) = make_uint4(LB0[0], LB0[1], LB0[2], LB0[3]);
    *(uint4*)(d0 + 12)= make_uint4(LB0[4], LB0[5], LB0[6], LB0[7]);
    unsigned* d1 = (unsigned*)(out + (size_t)(row0 + 16 + m) * NN) + sbase;
    *(uint4*)(d1)     = make_uint4(LA1[0], LA1[1], LA1[2], LA1[3]);
    *(uint4*)(d1 + 4) = make_uint4(LA1[4], LA1[5], LA1[6], LA1[7]);
    *(uint4*)(d1 + 8) = make_uint4(LB1[0], LB1[1], LB1[2], LB1[3]);
    *(uint4*)(d1 + 12)= make_uint4(LB1[4], LB1[5], LB1[6], LB1[7]);
    unsigned* d2 = (unsigned*)(out + (size_t)(row0 + 32 + m) * NN) + sbase;
    *(uint4*)(d2)     = make_uint4(LA2[0], LA2[1], LA2[2], LA2[3]);
    *(uint4*)(d2 + 4) = make_uint4(LA2[4], LA2[5], LA2[6], LA2[7]);
    *(uint4*)(d2 + 8) = make_uint4(LB2[0], LB2[1], LB2[2], LB2[3]);
    *(uint4*)(d2 + 12)= make_uint4(LB2[4], LB2[5], LB2[6], LB2[7]);
  }
}

// ---------------- Kernel 3: select + rescore + top-31 + prefix-zero + scatter ----------------
// R20: rescore widened to 16 candidates in flight per wave (4 per 16-lane
// group per iteration; ng ~ nc/16 ~ 6). Per-candidate dot math unchanged.
__global__ __launch_bounds__(256)
void select_kernel(const float* __restrict__ hnf, float* __restrict__ out) {
  __shared__ unsigned scand[4][CCAP];
  __shared__ double cres[4][CCAP];
  const int t = threadIdx.x, lane = t & 63, wv = t >> 6;
  const int row = blockIdx.x * 4 + wv;
  float* orow = out + (size_t)row * NN;

  unsigned k16[16];
  {
    const unsigned* src = (const unsigned*)orow + lane * 16;
    #pragma unroll
    for (int q = 0; q < 4; ++q) {
      uint4 a = *(const uint4*)(src + q * 4);
      k16[q * 4 + 0] = a.x; k16[q * 4 + 1] = a.y;
      k16[q * 4 + 2] = a.z; k16[q * 4 + 3] = a.w;
    }
  }

  unsigned lo = 0, hi = 0xFFFFu;
  while (lo < hi) {
    unsigned mid = (lo + hi + 1) >> 1;
    int c = 0;
    #pragma unroll
    for (int i = 0; i < 16; ++i) c += (int)((k16[i] >> 16) >= mid);
    #pragma unroll
    for (int d = 1; d < 64; d <<= 1) c += __shfl_xor(c, d);
    if (c >= TCAND) lo = mid; else hi = mid - 1;
  }
  const unsigned thr = lo;

  int cl = 0;
  #pragma unroll
  for (int i = 0; i < 16; ++i) cl += (int)((k16[i] >> 16) >= thr);
  int pre = cl;
  #pragma unroll
  for (int d = 1; d < 64; d <<= 1) {
    int y = __shfl_up(pre, d);
    if (lane >= d) pre += y;
  }
  const int total = __shfl(pre, 63);
  const int nc = total < CCAP ? total : CCAP;
  int slot = pre - cl;
  #pragma unroll
  for (int i = 0; i < 16; ++i) {
    if ((k16[i] >> 16) >= thr) {
      if (slot < CCAP) scand[wv][slot] = k16[i];
      ++slot;
    }
  }
  // same-wave LDS producer->consumer: compiler inserts lgkmcnt

  // phase 3: 16-candidate-in-flight rescore over fp32 vectors, fp64 accumulate
  const float* arow = hnf + (size_t)row * DD;
  const int g4 = lane >> 4;          // candidate group (0..3)
  const int kl = (lane & 15) * 8;    // this lane's 8-float chunk (32 B)
  float a[8];
  {
    f32x4 a03 = *(const f32x4*)(arow + kl);
    f32x4 a47 = *(const f32x4*)(arow + kl + 4);
    a[0] = a03.x; a[1] = a03.y; a[2] = a03.z; a[3] = a03.w;
    a[4] = a47.x; a[5] = a47.y; a[6] = a47.z; a[7] = a47.w;
  }
  const int ng = (nc + 15) >> 4;     // 4 candidates per group per iteration
  for (int g = 0; g < ng; ++g) {
    const int ci0 = 16 * g + g4;
    const int ci1 = ci0 + 4;
    const int ci2 = ci0 + 8;
    const int ci3 = ci0 + 12;
    double p0 = 0.0, p1 = 0.0, p2 = 0.0, p3 = 0.0;
    CDOT(ci0, p0)
    CDOT(ci1, p1)
    CDOT(ci2, p2)
    CDOT(ci3, p3)
    #pragma unroll
    for (int d = 1; d < 16; d <<= 1) {
      p0 += __shfl_xor(p0, d);
      p1 += __shfl_xor(p1, d);
      p2 += __shfl_xor(p2, d);
      p3 += __shfl_xor(p3, d);
    }
    if ((lane & 15) == 0) {
      if (ci0 < nc) cres[wv][ci0] = p0;
      if (ci1 < nc) cres[wv][ci1] = p1;
      if (ci2 < nc) cres[wv][ci2] = p2;
      if (ci3 < nc) cres[wv][ci3] = p3;
    }
  }
  double rv0 = -1.0e300, rv1 = -1.0e300;
  int rc0 = 0x7fffffff, rc1 = 0x7fffffff;
  if (lane < nc)      { rv0 = cres[wv][lane];      rc0 = (int)(scand[wv][lane] & 0xFFFFu); }
  if (lane + 64 < nc) { rv1 = cres[wv][lane + 64]; rc1 = (int)(scand[wv][lane + 64] & 0xFFFFu); }

  float fkv = 0.0f; int fkc = 0;
  for (int itk = 0; itk < KTOP; ++itk) {
    bool f = (rv0 > rv1) || (rv0 == rv1 && rc0 < rc1);
    double bv = f ? rv0 : rv1;
    int bc = f ? rc0 : rc1;
    #pragma unroll
    for (int d = 1; d < 64; d <<= 1) {
      double ov = __shfl_xor(bv, d);
      int    oc = __shfl_xor(bc, d);
      bool tk = (ov > bv) || (ov == bv && oc < bc);
      bv = tk ? ov : bv;
      bc = tk ? oc : bc;
    }
    if (lane == itk) { fkv = (float)fmax(bv, 0.0); fkc = bc; }
    if (rv0 == bv && rc0 == bc) rv0 = -1.0e300;
    else if (rv1 == bv && rc1 == bc) rv1 = -1.0e300;
  }

  // re-zero this row's 4 KB key prefix (cols 0-1023), drain, scatter
  {
    f32x4* zp = (f32x4*)orow;
    const f32x4 z = {0.0f, 0.0f, 0.0f, 0.0f};
    #pragma unroll
    for (int j = 0; j < 4; ++j)
      __builtin_nontemporal_store(z, &zp[j * 64 + lane]);
  }
  asm volatile("s_waitcnt vmcnt(0)" ::: "memory");
  if (lane < KTOP) orow[fkc] = fkv;
}

extern "C" void kernel_launch(void* const* d_in, const int* in_sizes, int n_in,
                              void* d_out, int out_size, void* d_ws, size_t ws_size,
                              hipStream_t stream) {
  const float* feat = (const float*)d_in[0];
  const float* W1 = (const float*)d_in[1];
  const float* b1 = (const float*)d_in[2];
  const float* W2 = (const float*)d_in[3];
  const float* b2 = (const float*)d_in[4];
  float* out = (float*)d_out;

  // ws: hnf fp32 (6.3 MB) | hnb bf16 (3.1 MB) | W1T,W2T (128 KB)
  float* hnf = (float*)d_ws;
  unsigned short* hnb = (unsigned short*)(hnf + (size_t)NN * DD);
  float* W1T = (float*)(hnb + (size_t)NN * DD);
  float* W2T = W1T + DD * DD;

  wtrans_kernel<<<DD, DD, 0, stream>>>(W1, W2, W1T, W2T);
  mlp_norm_kernel<<<NN / 16, 256, 0, stream>>>(feat, W1T, b1, W2T, b2, hnf, hnb);
  simloop_kernel<<<NN / RPB, 1024, 0, stream>>>(hnb, out);
  select_kernel<<<NN / 4, 256, 0, stream>>>(hnf, out);
}

// Round 21
// 859.897 us; speedup vs baseline: 1.0059x; 1.0059x over previous
//
#include <hip/hip_runtime.h>
#include <stdint.h>
#include <math.h>

#define NN 12288
#define DD 128
#define KTOP 31
#define TCAND 64         // candidate set >= top-64 by bf16 key (R0-R18-verified margin)
#define CCAP 128         // compaction capacity
#define RPB 48           // rows per loop-block; grid = 256 = 1 block/CU
#define WPL 16           // waves per loop block (1024 threads -> 4 waves/SIMD)
#define NIT 24           // column iterations: 12288 / (WPL*32)
#define KPROW 1024       // keys per row (128 streams x depth 8); 4 KB = row output prefix

typedef __attribute__((ext_vector_type(8))) short bf16x8;
typedef __attribute__((ext_vector_type(4))) float f32x4;

__device__ __forceinline__ unsigned short f2bf(float x) {  // RNE, no NaN in our data
  unsigned int u = __float_as_uint(x);
  u += 0x7fffu + ((u >> 16) & 1u);
  return (unsigned short)(u >> 16);
}

__device__ __forceinline__ unsigned umed3(unsigned a, unsigned b, unsigned c) {
  unsigned d;
  asm("v_med3_u32 %0, %1, %2, %3" : "=v"(d) : "v"(a), "v"(b), "v"(c));
  return d;
}

#define PINS8(Lx, P) { \
  const unsigned p_ = (P); \
  _Pragma("unroll") \
  for (int i_ = 0; i_ < 7; ++i_) \
    Lx[i_] = umed3(p_, Lx[i_], Lx[i_ + 1]); \
  Lx[7] = Lx[7] > p_ ? Lx[7] : p_; }

#define LKEY(ACC, LX, COLBASE) { \
  _Pragma("unroll") \
  for (int r_ = 0; r_ < 4; ++r_) { \
    unsigned bf_ = f2bf((ACC)[r_]); \
    unsigned s_ = (bf_ & 0x8000u) ? 0u : bf_; \
    unsigned p_k = (s_ << 16) | (unsigned)((COLBASE) + quad * 4 + r_); \
    PINS8(LX, p_k) } }

// ---------------- Kernel 0: transpose W1,W2 ----------------
__global__ __launch_bounds__(128)
void wtrans_kernel(const float* __restrict__ W1, const float* __restrict__ W2,
                   float* __restrict__ W1T, float* __restrict__ W2T) {
  const int r = blockIdx.x, c = threadIdx.x;
  W1T[(size_t)c * DD + r] = W1[(size_t)r * DD + c];
  W2T[(size_t)c * DD + r] = W2[(size_t)r * DD + c];
}

// ---------------- Kernel 1: MLP + L2 normalize ----------------
// bufB (post-ReLU) stored f32 -> layer-2 reads f32x4 per 4 k-steps (R19).
// Reference is fp32 end-to-end; f32-rounding perturbs ~1e-7 vs 4e-3 tolerance.
// Accumulation ORDER kept (k ascending); fp64 FMA chain otherwise unchanged.
__global__ __launch_bounds__(256)
void mlp_norm_kernel(const float* __restrict__ feat,
                     const float* __restrict__ W1T, const float* __restrict__ b1,
                     const float* __restrict__ W2T, const float* __restrict__ b2,
                     float* __restrict__ hnf, unsigned short* __restrict__ hnb) {
  __shared__ float  bufA[16][DD];    // 8 KB (f32 input, exact)
  __shared__ float  bufB[16][DD];    // 8 KB (f32 post-ReLU)
  __shared__ double bufC[16][DD];    // 16 KB
  __shared__ double mnorm[16];
  const int t = threadIdx.x;
  const int c = t & 127;
  const int g = t >> 7;
  const int row0 = blockIdx.x * 16 + g * 8;

  #pragma unroll
  for (int rr = 0; rr < 8; ++rr)
    bufA[g * 8 + rr][c] = feat[(size_t)(row0 + rr) * DD + c];
  __syncthreads();

  {
    double acc[8] = {0,0,0,0,0,0,0,0};
    for (int k = 0; k < DD; k += 4) {
      double w0 = (double)W1T[(size_t)k * DD + c];
      double w1 = (double)W1T[(size_t)(k + 1) * DD + c];
      double w2 = (double)W1T[(size_t)(k + 2) * DD + c];
      double w3 = (double)W1T[(size_t)(k + 3) * DD + c];
      #pragma unroll
      for (int rr = 0; rr < 8; ++rr) {
        f32x4 a4 = *(const f32x4*)(&bufA[g * 8 + rr][k]);
        acc[rr] = fma(w0, (double)a4.x, acc[rr]);
        acc[rr] = fma(w1, (double)a4.y, acc[rr]);
        acc[rr] = fma(w2, (double)a4.z, acc[rr]);
        acc[rr] = fma(w3, (double)a4.w, acc[rr]);
      }
    }
    double bb = (double)b1[c];
    #pragma unroll
    for (int rr = 0; rr < 8; ++rr)
      bufB[g * 8 + rr][c] = (float)fmax(acc[rr] + bb, 0.0);
  }
  __syncthreads();
  {
    double acc[8] = {0,0,0,0,0,0,0,0};
    for (int k = 0; k < DD; k += 4) {
      double w0 = (double)W2T[(size_t)k * DD + c];
      double w1 = (double)W2T[(size_t)(k + 1) * DD + c];
      double w2 = (double)W2T[(size_t)(k + 2) * DD + c];
      double w3 = (double)W2T[(size_t)(k + 3) * DD + c];
      #pragma unroll
      for (int rr = 0; rr < 8; ++rr) {
        f32x4 a4 = *(const f32x4*)(&bufB[g * 8 + rr][k]);
        acc[rr] = fma(w0, (double)a4.x, acc[rr]);
        acc[rr] = fma(w1, (double)a4.y, acc[rr]);
        acc[rr] = fma(w2, (double)a4.z, acc[rr]);
        acc[rr] = fma(w3, (double)a4.w, acc[rr]);
      }
    }
    double bb = (double)b2[c];
    #pragma unroll
    for (int rr = 0; rr < 8; ++rr)
      bufC[g * 8 + rr][c] = acc[rr] + bb;
  }
  __syncthreads();

  const int lane = t & 63;
  const int w = t >> 6;
  #pragma unroll
  for (int r2 = 0; r2 < 4; ++r2) {
    int rr = w * 4 + r2;
    double x0 = bufC[rr][lane];
    double x1 = bufC[rr][lane + 64];
    double s = x0 * x0 + x1 * x1;
    #pragma unroll
    for (int d = 1; d < 64; d <<= 1)
      s += __shfl_xor(s, d);
    if (lane == 0) mnorm[rr] = fmax(sqrt(s), 1e-12);
  }
  __syncthreads();
  #pragma unroll
  for (int rr = 0; rr < 8; ++rr) {
    double v = bufC[g * 8 + rr][c] / mnorm[g * 8 + rr];
    float vf = (float)v;
    hnf[(size_t)(row0 + rr) * DD + c] = vf;
    hnb[(size_t)(row0 + rr) * DD + c] = f2bf(vf);
  }
}

// ---------------- Kernel 2: sim MFMA loop + ladders + in-loop zeros; keys -> row prefix ----------------
// Prefix region (cols 0-1023 of each row) never zeroed here (dead stores; keys
// overwrite, select re-zeros). No zero/key aliasing -> no pre-dump drain.
// Stagger: same-XCD blocks start at 8 different column phases.
__global__ __launch_bounds__(1024)
void simloop_kernel(const unsigned short* __restrict__ hnb,
                    float* __restrict__ out) {
  const int t = threadIdx.x, lane = t & 63, wv = t >> 6;   // wv 0..15
  const int m = lane & 15, quad = lane >> 4;
  const int row0 = blockIdx.x * RPB;
  const int it0 = (int)(((blockIdx.x >> 3) * 3u) % NIT);   // same-XCD phase spread
  const bool pfx = (t < 256);                              // prefix-owning threads

  bf16x8 af0[4], af1[4], af2[4];
  #pragma unroll
  for (int kc = 0; kc < 4; ++kc) {
    af0[kc] = *(const bf16x8*)(hnb + (size_t)(row0 + m) * DD + kc * 32 + quad * 8);
    af1[kc] = *(const bf16x8*)(hnb + (size_t)(row0 + 16 + m) * DD + kc * 32 + quad * 8);
    af2[kc] = *(const bf16x8*)(hnb + (size_t)(row0 + 32 + m) * DD + kc * 32 + quad * 8);
  }

  unsigned LA0[8] = {0,0,0,0,0,0,0,0}, LB0[8] = {0,0,0,0,0,0,0,0};
  unsigned LA1[8] = {0,0,0,0,0,0,0,0}, LB1[8] = {0,0,0,0,0,0,0,0};
  unsigned LA2[8] = {0,0,0,0,0,0,0,0}, LB2[8] = {0,0,0,0,0,0,0,0};

  f32x4* outz = (f32x4*)(out + (size_t)row0 * NN);   // 48 rows = 147456 f32x4
  const f32x4 z = {0.0f, 0.0f, 0.0f, 0.0f};

  for (int itt = 0; itt < NIT; ++itt) {
    int it = itt + it0; if (it >= NIT) it -= NIT;    // staggered column phase
    const int cb = it * (WPL * 32) + wv * 32;
    f32x4 a00 = {0,0,0,0}, a01 = {0,0,0,0};
    f32x4 a10 = {0,0,0,0}, a11 = {0,0,0,0};
    f32x4 a20 = {0,0,0,0}, a21 = {0,0,0,0};
    #pragma unroll
    for (int kc = 0; kc < 4; ++kc) {    // per-kc B loads: caps VGPR for 16-wave block
      bf16x8 b0 = *(const bf16x8*)(hnb + (size_t)(cb + m) * DD + kc * 32 + quad * 8);
      bf16x8 b1 = *(const bf16x8*)(hnb + (size_t)(cb + 16 + m) * DD + kc * 32 + quad * 8);
      a00 = __builtin_amdgcn_mfma_f32_16x16x32_bf16(b0, af0[kc], a00, 0, 0, 0);
      a01 = __builtin_amdgcn_mfma_f32_16x16x32_bf16(b1, af0[kc], a01, 0, 0, 0);
      a10 = __builtin_amdgcn_mfma_f32_16x16x32_bf16(b0, af1[kc], a10, 0, 0, 0);
      a11 = __builtin_amdgcn_mfma_f32_16x16x32_bf16(b1, af1[kc], a11, 0, 0, 0);
      a20 = __builtin_amdgcn_mfma_f32_16x16x32_bf16(b0, af2[kc], a20, 0, 0, 0);
      a21 = __builtin_amdgcn_mfma_f32_16x16x32_bf16(b1, af2[kc], a21, 0, 0, 0);
    }
    // in-loop NT zeros (6 f32x4/thread/iter); j==0 and j==3 land on row
    // prefixes for t<256 — skipped (keys own those bytes; select re-zeros).
    if (!pfx) __builtin_nontemporal_store(z, &outz[it * 6144 + t]);
    __builtin_nontemporal_store(z, &outz[it * 6144 + 1024 + t]);
    __builtin_nontemporal_store(z, &outz[it * 6144 + 2048 + t]);
    if (!pfx) __builtin_nontemporal_store(z, &outz[it * 6144 + 3072 + t]);
    __builtin_nontemporal_store(z, &outz[it * 6144 + 4096 + t]);
    __builtin_nontemporal_store(z, &outz[it * 6144 + 5120 + t]);
    LKEY(a00, LA0, cb)      LKEY(a01, LB0, cb + 16)
    LKEY(a10, LA1, cb)      LKEY(a11, LB1, cb + 16)
    LKEY(a20, LA2, cb)      LKEY(a21, LB2, cb + 16)
  }

  // key dump: no aliasing with the zero stream (prefix never zeroed) -> no
  // drain, no barrier; kernel-end drains everything before select launches.
  const int sbase = (wv * 4 + quad) * 16;   // 64 slots x 16 u32 = 1024 keys/row
  {
    unsigned* d0 = (unsigned*)(out + (size_t)(row0 + m) * NN) + sbase;
    *(uint4*)(d0)     = make_uint4(LA0[0], LA0[1], LA0[2], LA0[3]);
    *(uint4*)(d0 + 4) = make_uint4(LA0[4], LA0[5], LA0[6], LA0[7]);
    *(uint4*)(d0 + 8) = make_uint4(LB0[0], LB0[1], LB0[2], LB0[3]);
    *(uint4*)(d0 + 12)= make_uint4(LB0[4], LB0[5], LB0[6], LB0[7]);
    unsigned* d1 = (unsigned*)(out + (size_t)(row0 + 16 + m) * NN) + sbase;
    *(uint4*)(d1)     = make_uint4(LA1[0], LA1[1], LA1[2], LA1[3]);
    *(uint4*)(d1 + 4) = make_uint4(LA1[4], LA1[5], LA1[6], LA1[7]);
    *(uint4*)(d1 + 8) = make_uint4(LB1[0], LB1[1], LB1[2], LB1[3]);
    *(uint4*)(d1 + 12)= make_uint4(LB1[4], LB1[5], LB1[6], LB1[7]);
    unsigned* d2 = (unsigned*)(out + (size_t)(row0 + 32 + m) * NN) + sbase;
    *(uint4*)(d2)     = make_uint4(LA2[0], LA2[1], LA2[2], LA2[3]);
    *(uint4*)(d2 + 4) = make_uint4(LA2[4], LA2[5], LA2[6], LA2[7]);
    *(uint4*)(d2 + 8) = make_uint4(LB2[0], LB2[1], LB2[2], LB2[3]);
    *(uint4*)(d2 + 12)= make_uint4(LB2[4], LB2[5], LB2[6], LB2[7]);
  }
}

// ---------------- Kernel 3: select + rescore + top-31 + prefix-zero + scatter ----------------
// fp32 gathers (R18), 8 candidates in flight (R13/R14), fp64 accumulate.
__global__ __launch_bounds__(256)
void select_kernel(const float* __restrict__ hnf, float* __restrict__ out) {
  __shared__ unsigned scand[4][CCAP];
  __shared__ double cres[4][CCAP];
  const int t = threadIdx.x, lane = t & 63, wv = t >> 6;
  const int row = blockIdx.x * 4 + wv;
  float* orow = out + (size_t)row * NN;

  unsigned k16[16];
  {
    const unsigned* src = (const unsigned*)orow + lane * 16;
    #pragma unroll
    for (int q = 0; q < 4; ++q) {
      uint4 a = *(const uint4*)(src + q * 4);
      k16[q * 4 + 0] = a.x; k16[q * 4 + 1] = a.y;
      k16[q * 4 + 2] = a.z; k16[q * 4 + 3] = a.w;
    }
  }

  unsigned lo = 0, hi = 0xFFFFu;
  while (lo < hi) {
    unsigned mid = (lo + hi + 1) >> 1;
    int c = 0;
    #pragma unroll
    for (int i = 0; i < 16; ++i) c += (int)((k16[i] >> 16) >= mid);
    #pragma unroll
    for (int d = 1; d < 64; d <<= 1) c += __shfl_xor(c, d);
    if (c >= TCAND) lo = mid; else hi = mid - 1;
  }
  const unsigned thr = lo;

  int cl = 0;
  #pragma unroll
  for (int i = 0; i < 16; ++i) cl += (int)((k16[i] >> 16) >= thr);
  int pre = cl;
  #pragma unroll
  for (int d = 1; d < 64; d <<= 1) {
    int y = __shfl_up(pre, d);
    if (lane >= d) pre += y;
  }
  const int total = __shfl(pre, 63);
  const int nc = total < CCAP ? total : CCAP;
  int slot = pre - cl;
  #pragma unroll
  for (int i = 0; i < 16; ++i) {
    if ((k16[i] >> 16) >= thr) {
      if (slot < CCAP) scand[wv][slot] = k16[i];
      ++slot;
    }
  }
  // same-wave LDS producer->consumer: compiler inserts lgkmcnt

  // phase 3: 8-candidate-in-flight rescore over fp32 vectors, fp64 accumulate
  const float* arow = hnf + (size_t)row * DD;
  const int g4 = lane >> 4;          // candidate group (0..3)
  const int kl = (lane & 15) * 8;    // this lane's 8-float chunk (32 B)
  float a[8];
  {
    f32x4 a03 = *(const f32x4*)(arow + kl);
    f32x4 a47 = *(const f32x4*)(arow + kl + 4);
    a[0] = a03.x; a[1] = a03.y; a[2] = a03.z; a[3] = a03.w;
    a[4] = a47.x; a[5] = a47.y; a[6] = a47.z; a[7] = a47.w;
  }
  const int ng = (nc + 7) >> 3;      // 2 candidates per group per iteration
  for (int g = 0; g < ng; ++g) {
    const int ci0 = 8 * g + g4;
    const int ci1 = ci0 + 4;
    double p0 = 0.0, p1 = 0.0;
    if (ci0 < nc) {
      const int col = (int)(scand[wv][ci0] & 0xFFFFu);
      const float* brow = hnf + (size_t)col * DD + kl;
      f32x4 b03 = *(const f32x4*)(brow);
      f32x4 b47 = *(const f32x4*)(brow + 4);
      p0 = fma((double)a[0], (double)b03.x, fma((double)a[1], (double)b03.y,
           fma((double)a[2], (double)b03.z, (double)a[3] * (double)b03.w)));
      p0 = fma((double)a[4], (double)b47.x, fma((double)a[5], (double)b47.y,
           fma((double)a[6], (double)b47.z, fma((double)a[7], (double)b47.w, p0))));
    }
    if (ci1 < nc) {
      const int col = (int)(scand[wv][ci1] & 0xFFFFu);
      const float* brow = hnf + (size_t)col * DD + kl;
      f32x4 b03 = *(const f32x4*)(brow);
      f32x4 b47 = *(const f32x4*)(brow + 4);
      p1 = fma((double)a[0], (double)b03.x, fma((double)a[1], (double)b03.y,
           fma((double)a[2], (double)b03.z, (double)a[3] * (double)b03.w)));
      p1 = fma((double)a[4], (double)b47.x, fma((double)a[5], (double)b47.y,
           fma((double)a[6], (double)b47.z, fma((double)a[7], (double)b47.w, p1))));
    }
    #pragma unroll
    for (int d = 1; d < 16; d <<= 1) {
      p0 += __shfl_xor(p0, d);
      p1 += __shfl_xor(p1, d);
    }
    if ((lane & 15) == 0) {
      if (ci0 < nc) cres[wv][ci0] = p0;
      if (ci1 < nc) cres[wv][ci1] = p1;
    }
  }
  double rv0 = -1.0e300, rv1 = -1.0e300;
  int rc0 = 0x7fffffff, rc1 = 0x7fffffff;
  if (lane < nc)      { rv0 = cres[wv][lane];      rc0 = (int)(scand[wv][lane] & 0xFFFFu); }
  if (lane + 64 < nc) { rv1 = cres[wv][lane + 64]; rc1 = (int)(scand[wv][lane + 64] & 0xFFFFu); }

  float fkv = 0.0f; int fkc = 0;
  for (int itk = 0; itk < KTOP; ++itk) {
    bool f = (rv0 > rv1) || (rv0 == rv1 && rc0 < rc1);
    double bv = f ? rv0 : rv1;
    int bc = f ? rc0 : rc1;
    #pragma unroll
    for (int d = 1; d < 64; d <<= 1) {
      double ov = __shfl_xor(bv, d);
      int    oc = __shfl_xor(bc, d);
      bool tk = (ov > bv) || (ov == bv && oc < bc);
      bv = tk ? ov : bv;
      bc = tk ? oc : bc;
    }
    if (lane == itk) { fkv = (float)fmax(bv, 0.0); fkc = bc; }
    if (rv0 == bv && rc0 == bc) rv0 = -1.0e300;
    else if (rv1 == bv && rc1 == bc) rv1 = -1.0e300;
  }

  // re-zero this row's 4 KB key prefix (cols 0-1023), drain, scatter
  {
    f32x4* zp = (f32x4*)orow;
    const f32x4 z = {0.0f, 0.0f, 0.0f, 0.0f};
    #pragma unroll
    for (int j = 0; j < 4; ++j)
      __builtin_nontemporal_store(z, &zp[j * 64 + lane]);
  }
  asm volatile("s_waitcnt vmcnt(0)" ::: "memory");
  if (lane < KTOP) orow[fkc] = fkv;
}

extern "C" void kernel_launch(void* const* d_in, const int* in_sizes, int n_in,
                              void* d_out, int out_size, void* d_ws, size_t ws_size,
                              hipStream_t stream) {
  const float* feat = (const float*)d_in[0];
  const float* W1 = (const float*)d_in[1];
  const float* b1 = (const float*)d_in[2];
  const float* W2 = (const float*)d_in[3];
  const float* b2 = (const float*)d_in[4];
  float* out = (float*)d_out;

  // ws: hnf fp32 (6.3 MB) | hnb bf16 (3.1 MB) | W1T,W2T (128 KB)
  float* hnf = (float*)d_ws;
  unsigned short* hnb = (unsigned short*)(hnf + (size_t)NN * DD);
  float* W1T = (float*)(hnb + (size_t)NN * DD);
  float* W2T = W1T + DD * DD;

  wtrans_kernel<<<DD, DD, 0, stream>>>(W1, W2, W1T, W2T);
  mlp_norm_kernel<<<NN / 16, 256, 0, stream>>>(feat, W1T, b1, W2T, b2, hnf, hnb);
  simloop_kernel<<<NN / RPB, 1024, 0, stream>>>(hnb, out);
  select_kernel<<<NN / 4, 256, 0, stream>>>(hnf, out);
}